// Round 1
// baseline (1365.083 us; speedup 1.0000x reference)
//
#include <hip/hip_runtime.h>
#include <hip/hip_bf16.h>
#include <hip/hip_fp16.h>

// ManualRNN: B=32, T=2048, Fin=256, H=256, O=256  (all f32 in/out)
//   phase1: xh = x @ Wxh^T + bxh      (65536x256 @ 256x256^T)   -> stored f32 in d_out's y region
//   phase2: h_t = tanh(xh_t + h @ Whh^T), scan over T            -> hs stored f16 in d_ws
//   phase3: y  = hs @ Why^T + by                                 -> overwrites d_out y region
// h_final (32x256 f32) at d_out + 65536*256.

typedef _Float16 f16x8 __attribute__((ext_vector_type(8)));
typedef float    f32x4 __attribute__((ext_vector_type(4)));

#define MFMA16 __builtin_amdgcn_mfma_f32_16x16x32_f16

__device__ __forceinline__ f16x8 cvt8(const float* __restrict__ p) {
    float4 u = *(const float4*)p;
    float4 v = *(const float4*)(p + 4);
    f16x8 r;
    r[0] = (_Float16)u.x; r[1] = (_Float16)u.y; r[2] = (_Float16)u.z; r[3] = (_Float16)u.w;
    r[4] = (_Float16)v.x; r[5] = (_Float16)v.y; r[6] = (_Float16)v.z; r[7] = (_Float16)v.w;
    return r;
}

// C[m][n] = sum_k A[m][k] * W[n][k] + bias[n];  M = gridDim.x*64, N = K = 256.
// Block: 256 threads = 4 waves; block tile 64(M) x 256(N); wave w owns n-chunk w*64.
template<bool AF16>
__global__ __launch_bounds__(256, 2) void gemm_nt_256(
    const void* __restrict__ Av, const float* __restrict__ W,
    const float* __restrict__ bias, float* __restrict__ C) {
    const int tid = threadIdx.x;
    const int l  = tid & 63;
    const int w  = tid >> 6;
    const int lr = l & 15;          // row/col within 16-tile
    const int lg = l >> 4;          // k-group (0..3)
    const long m0 = (long)blockIdx.x * 64;
    const int  n0 = w * 64;

    f32x4 acc[4][4] = {};           // [mt][nt]

    #pragma unroll
    for (int k = 0; k < 8; ++k) {   // K = 8 * 32
        const int kc = k * 32 + lg * 8;
        f16x8 a[4], bf[4];
        #pragma unroll
        for (int mt = 0; mt < 4; ++mt) {
            const long row = m0 + mt * 16 + lr;
            if constexpr (AF16)
                a[mt] = *(const f16x8*)((const _Float16*)Av + row * 256 + kc);
            else
                a[mt] = cvt8((const float*)Av + row * 256 + kc);
        }
        #pragma unroll
        for (int nt = 0; nt < 4; ++nt)
            bf[nt] = cvt8(W + (long)(n0 + nt * 16 + lr) * 256 + kc);
        #pragma unroll
        for (int mt = 0; mt < 4; ++mt)
            #pragma unroll
            for (int nt = 0; nt < 4; ++nt)
                acc[mt][nt] = MFMA16(a[mt], bf[nt], acc[mt][nt], 0, 0, 0);
    }

    // D: lane l holds C[row=(l>>4)*4+d][col=l&15] per 16x16 tile (verified layout)
    #pragma unroll
    for (int mt = 0; mt < 4; ++mt)
        #pragma unroll
        for (int nt = 0; nt < 4; ++nt) {
            const int col = n0 + nt * 16 + lr;
            const float bv = bias[col];
            #pragma unroll
            for (int d = 0; d < 4; ++d) {
                const long row = m0 + mt * 16 + lg * 4 + d;
                C[row * 256 + col] = acc[mt][nt][d] + bv;
            }
        }
}

// Recurrence: 32 blocks (1 batch each) x 256 threads (4 waves).
// Whh held in registers as MFMA B-fragments (wave w owns outputs n0=w*64..+63).
// h broadcast via double-buffered LDS row (f16). All 16 lanes of a k-group read
// the same LDS address -> broadcast, and every A-tile row equals h, so every
// C row equals s = Whh·h (no garbage-row hazard; use reg 0).
__global__ __launch_bounds__(256, 1) void rnn_scan(
    const float* __restrict__ xh, const float* __restrict__ h0,
    const float* __restrict__ Whh, _Float16* __restrict__ hs,
    float* __restrict__ hfin) {
    const int b   = blockIdx.x;
    const int tid = threadIdx.x;
    const int l   = tid & 63;
    const int w   = tid >> 6;
    const int lr  = l & 15;
    const int lg  = l >> 4;
    const int n0  = w * 64;

    __shared__ _Float16 hbuf[2][256];

    // Load Whh fragments: wb[nt][k] = Whh[n0+nt*16+lr][k*32+lg*8 .. +8]  (128 VGPRs)
    f16x8 wb[4][8];
    #pragma unroll
    for (int nt = 0; nt < 4; ++nt)
        #pragma unroll
        for (int k = 0; k < 8; ++k)
            wb[nt][k] = cvt8(Whh + (long)(n0 + nt * 16 + lr) * 256 + k * 32 + lg * 8);

    hbuf[0][tid] = (_Float16)h0[b * 256 + tid];
    __syncthreads();

    const float* xp = xh + (long)b * 2048 * 256;
    float xc[4], xn[4];
    #pragma unroll
    for (int nt = 0; nt < 4; ++nt) xc[nt] = xp[n0 + nt * 16 + lr];

    for (int t = 0; t < 2048; ++t) {
        const int cur = t & 1;

        // prefetch next step's xh (hidden under MFMAs)
        const int tn = (t + 1 < 2048) ? (t + 1) : 2047;
        const float* xq = xp + (long)tn * 256;
        #pragma unroll
        for (int nt = 0; nt < 4; ++nt) xn[nt] = xq[n0 + nt * 16 + lr];

        // A fragments: broadcast h (same addr across the 16 lanes of each k-group)
        const f16x8* hc = (const f16x8*)hbuf[cur];
        f16x8 af[8];
        #pragma unroll
        for (int k = 0; k < 8; ++k) af[k] = hc[k * 4 + lg];

        f32x4 zero = {0.f, 0.f, 0.f, 0.f};
        f32x4 acc[4];
        #pragma unroll
        for (int nt = 0; nt < 4; ++nt) acc[nt] = MFMA16(af[0], wb[nt][0], zero, 0, 0, 0);
        #pragma unroll
        for (int k = 1; k < 8; ++k)
            #pragma unroll
            for (int nt = 0; nt < 4; ++nt)
                acc[nt] = MFMA16(af[k], wb[nt][k], acc[nt], 0, 0, 0);

        // tanh(s + xh):   tanh(x) = 1 - 2/(exp(2x)+1)   (saturates correctly at +-inf)
        float tv[4];
        #pragma unroll
        for (int nt = 0; nt < 4; ++nt) {
            const float s = acc[nt][0] + xc[nt];
            const float e = __expf(2.0f * s);
            tv[nt] = 1.0f - 2.0f * __builtin_amdgcn_rcpf(e + 1.0f);
        }

        if (l < 16) {
            _Float16* hn = hbuf[cur ^ 1];
            #pragma unroll
            for (int nt = 0; nt < 4; ++nt) {
                const int n = n0 + nt * 16 + l;
                const _Float16 hv = (_Float16)tv[nt];
                hn[n] = hv;
                hs[((long)b * 2048 + t) * 256 + n] = hv;
            }
            if (t == 2047) {
                #pragma unroll
                for (int nt = 0; nt < 4; ++nt)
                    hfin[b * 256 + n0 + nt * 16 + l] = tv[nt];
            }
        }

        #pragma unroll
        for (int nt = 0; nt < 4; ++nt) xc[nt] = xn[nt];
        __syncthreads();
    }
}

extern "C" void kernel_launch(void* const* d_in, const int* in_sizes, int n_in,
                              void* d_out, int out_size, void* d_ws, size_t ws_size,
                              hipStream_t stream) {
    const float* x   = (const float*)d_in[0];  // (32,2048,256)
    const float* h0  = (const float*)d_in[1];  // (32,256)
    const float* Wxh = (const float*)d_in[2];  // (256,256)
    const float* bxh = (const float*)d_in[3];  // (256,)
    const float* Whh = (const float*)d_in[4];  // (256,256)
    const float* Why = (const float*)d_in[5];  // (256,256)
    const float* by  = (const float*)d_in[6];  // (256,)

    float* y    = (float*)d_out;                   // (65536,256) f32
    float* hfin = y + (long)65536 * 256;           // (32,256) f32
    float* xh   = y;                               // reuse y region as xh scratch (dead before phase3 writes)
    _Float16* hs = (_Float16*)d_ws;                // (65536,256) f16 = 33.5 MB

    // phase 1: xh = x @ Wxh^T + bxh
    gemm_nt_256<false><<<1024, 256, 0, stream>>>(x, Wxh, bxh, xh);
    // phase 2: sequential scan, one block per batch row
    rnn_scan<<<32, 256, 0, stream>>>(xh, h0, Whh, hs, hfin);
    // phase 3: y = hs @ Why^T + by
    gemm_nt_256<true><<<1024, 256, 0, stream>>>(hs, Why, by, y);
}

// Round 2
// 1202.912 us; speedup vs baseline: 1.1348x; 1.1348x over previous
//
#include <hip/hip_runtime.h>
#include <hip/hip_bf16.h>
#include <hip/hip_fp16.h>

// ManualRNN: B=32, T=2048, Fin=256, H=256, O=256  (all f32 in/out)
//   phase1: xh = x @ Wxh^T + bxh   -> stored f32 in d_out's y region (dead before phase3)
//   phase2: h_t = tanh(xh_t + h @ Whh^T), scan over T -> hs f16 in d_ws
//   phase3: y  = hs @ Why^T + by   -> overwrites y region
// h_final (32x256 f32) at d_out + 65536*256.

typedef _Float16 f16x8 __attribute__((ext_vector_type(8)));
typedef float    f32x4 __attribute__((ext_vector_type(4)));

#define MFMA16 __builtin_amdgcn_mfma_f32_16x16x32_f16

__device__ __forceinline__ f16x8 cvt8(const float* __restrict__ p) {
    float4 u = *(const float4*)p;
    float4 v = *(const float4*)(p + 4);
    f16x8 r;
    r[0] = (_Float16)u.x; r[1] = (_Float16)u.y; r[2] = (_Float16)u.z; r[3] = (_Float16)u.w;
    r[4] = (_Float16)v.x; r[5] = (_Float16)v.y; r[6] = (_Float16)v.z; r[7] = (_Float16)v.w;
    return r;
}

// C[m][n] = sum_k A[m][k] * W[n][k] + bias[n];  M = gridDim.x*64, N = K = 256.
template<bool AF16>
__global__ __launch_bounds__(256, 2) void gemm_nt_256(
    const void* __restrict__ Av, const float* __restrict__ W,
    const float* __restrict__ bias, float* __restrict__ C) {
    const int tid = threadIdx.x;
    const int l  = tid & 63;
    const int w  = tid >> 6;
    const int lr = l & 15;
    const int lg = l >> 4;
    const long m0 = (long)blockIdx.x * 64;
    const int  n0 = w * 64;

    f32x4 acc[4][4] = {};

    #pragma unroll
    for (int k = 0; k < 8; ++k) {
        const int kc = k * 32 + lg * 8;
        f16x8 a[4], bf[4];
        #pragma unroll
        for (int mt = 0; mt < 4; ++mt) {
            const long row = m0 + mt * 16 + lr;
            if constexpr (AF16)
                a[mt] = *(const f16x8*)((const _Float16*)Av + row * 256 + kc);
            else
                a[mt] = cvt8((const float*)Av + row * 256 + kc);
        }
        #pragma unroll
        for (int nt = 0; nt < 4; ++nt)
            bf[nt] = cvt8(W + (long)(n0 + nt * 16 + lr) * 256 + kc);
        #pragma unroll
        for (int mt = 0; mt < 4; ++mt)
            #pragma unroll
            for (int nt = 0; nt < 4; ++nt)
                acc[mt][nt] = MFMA16(a[mt], bf[nt], acc[mt][nt], 0, 0, 0);
    }

    #pragma unroll
    for (int mt = 0; mt < 4; ++mt)
        #pragma unroll
        for (int nt = 0; nt < 4; ++nt) {
            const int col = n0 + nt * 16 + lr;
            const float bv = bias[col];
            #pragma unroll
            for (int d = 0; d < 4; ++d) {
                const long row = m0 + mt * 16 + lg * 4 + d;
                C[row * 256 + col] = acc[mt][nt][d] + bv;
            }
        }
}

// Recurrence: 32 blocks (1 batch each) x 512 threads (8 waves, 2/SIMD for overlap).
// Wave w owns outputs n0=w*32 (2 n-tiles). Whh B-fragments in registers (64 VGPR).
// h broadcast via double-buffered LDS row. Raw s_barrier with lgkmcnt(0)-only wait:
// the hs global stores and xh prefetch loads are NOT drained per step (vs
// __syncthreads' vmcnt(0) drain, which cost ~half the step time in r1).
__global__ __launch_bounds__(512, 1) void rnn_scan(
    const float* __restrict__ xh, const float* __restrict__ h0,
    const float* __restrict__ Whh, _Float16* __restrict__ hs,
    float* __restrict__ hfin) {
    const int b   = blockIdx.x;
    const int tid = threadIdx.x;
    const int l   = tid & 63;
    const int w   = tid >> 6;   // 0..7
    const int lr  = l & 15;
    const int lg  = l >> 4;
    const int n0  = w * 32;

    __shared__ _Float16 hbuf[2][256];

    // wb[nt][k] = Whh[n0+nt*16+lr][k*32+lg*8 .. +8]
    f16x8 wb[2][8];
    #pragma unroll
    for (int nt = 0; nt < 2; ++nt)
        #pragma unroll
        for (int k = 0; k < 8; ++k)
            wb[nt][k] = cvt8(Whh + (long)(n0 + nt * 16 + lr) * 256 + k * 32 + lg * 8);

    if (tid < 256) hbuf[0][tid] = (_Float16)h0[b * 256 + tid];
    __syncthreads();

    const float* xp = xh + (long)b * 2048 * 256;
    float xc[2], xn[2];
    #pragma unroll
    for (int nt = 0; nt < 2; ++nt) xc[nt] = xp[n0 + nt * 16 + lr];

    for (int t = 0; t < 2048; ++t) {
        const int cur = t & 1;

        // prefetch next step's xh (off critical path; no vmcnt drain in loop)
        const int tn = (t + 1 < 2048) ? (t + 1) : 2047;
        const float* xq = xp + (long)tn * 256;
        #pragma unroll
        for (int nt = 0; nt < 2; ++nt) xn[nt] = xq[n0 + nt * 16 + lr];

        // A fragments: LDS broadcast (16 lanes/group read same 16B line)
        const f16x8* hc = (const f16x8*)hbuf[cur];
        f16x8 af[8];
        #pragma unroll
        for (int k = 0; k < 8; ++k) af[k] = hc[k * 4 + lg];

        f32x4 zero = {0.f, 0.f, 0.f, 0.f};
        f32x4 acc[2];
        #pragma unroll
        for (int nt = 0; nt < 2; ++nt) acc[nt] = MFMA16(af[0], wb[nt][0], zero, 0, 0, 0);
        #pragma unroll
        for (int k = 1; k < 8; ++k)
            #pragma unroll
            for (int nt = 0; nt < 2; ++nt)
                acc[nt] = MFMA16(af[k], wb[nt][k], acc[nt], 0, 0, 0);

        // tanh(s + xh) = 1 - 2/(exp(2s)+1)
        float tv[2];
        #pragma unroll
        for (int nt = 0; nt < 2; ++nt) {
            const float s = acc[nt][0] + xc[nt];
            const float e = __expf(2.0f * s);
            tv[nt] = 1.0f - 2.0f * __builtin_amdgcn_rcpf(e + 1.0f);
        }

        if (l < 16) {
            _Float16* hn = hbuf[cur ^ 1];
            #pragma unroll
            for (int nt = 0; nt < 2; ++nt) {
                const int n = n0 + nt * 16 + l;
                const _Float16 hv = (_Float16)tv[nt];
                hn[n] = hv;
                hs[((long)b * 2048 + t) * 256 + n] = hv;   // fire-and-forget
            }
            if (t == 2047) {
                #pragma unroll
                for (int nt = 0; nt < 2; ++nt)
                    hfin[b * 256 + n0 + nt * 16 + l] = tv[nt];
            }
        }

        #pragma unroll
        for (int nt = 0; nt < 2; ++nt) xc[nt] = xn[nt];

        // LDS-only barrier: order ds_write/ds_read across waves without
        // draining global stores (vmcnt). Sandwiched memory clobbers keep the
        // compiler from hoisting next iteration's ds_reads above the barrier.
        asm volatile("s_waitcnt lgkmcnt(0)" ::: "memory");
        __builtin_amdgcn_s_barrier();
        asm volatile("" ::: "memory");
    }
}

extern "C" void kernel_launch(void* const* d_in, const int* in_sizes, int n_in,
                              void* d_out, int out_size, void* d_ws, size_t ws_size,
                              hipStream_t stream) {
    const float* x   = (const float*)d_in[0];
    const float* h0  = (const float*)d_in[1];
    const float* Wxh = (const float*)d_in[2];
    const float* bxh = (const float*)d_in[3];
    const float* Whh = (const float*)d_in[4];
    const float* Why = (const float*)d_in[5];
    const float* by  = (const float*)d_in[6];

    float* y    = (float*)d_out;
    float* hfin = y + (long)65536 * 256;
    float* xh   = y;                       // xh scratch aliases y (dead before phase3 writes)
    _Float16* hs = (_Float16*)d_ws;

    gemm_nt_256<false><<<1024, 256, 0, stream>>>(x, Wxh, bxh, xh);
    rnn_scan<<<32, 512, 0, stream>>>(xh, h0, Whh, hs, hfin);
    gemm_nt_256<true><<<1024, 256, 0, stream>>>(hs, Why, by, y);
}

// Round 3
// 933.964 us; speedup vs baseline: 1.4616x; 1.2880x over previous
//
#include <hip/hip_runtime.h>
#include <hip/hip_bf16.h>
#include <hip/hip_fp16.h>

// ManualRNN: B=32, T=2048, Fin=256, H=256, O=256  (all f32 in/out)
//   phase1: xh = x @ Wxh^T + bxh   -> stored f32 in d_out's y region (dead before phase3)
//   phase2: h_t = tanh(xh_t + h @ Whh^T), scan over T -> hs f16 in d_ws
//   phase3: y  = hs @ Why^T + by   -> overwrites y region
// h_final (32x256 f32) at d_out + 65536*256.

typedef _Float16 f16x8 __attribute__((ext_vector_type(8)));
typedef float    f32x4 __attribute__((ext_vector_type(4)));

#define MFMA16 __builtin_amdgcn_mfma_f32_16x16x32_f16

__device__ __forceinline__ f16x8 cvt8(const float* __restrict__ p) {
    float4 u = *(const float4*)p;
    float4 v = *(const float4*)(p + 4);
    f16x8 r;
    r[0] = (_Float16)u.x; r[1] = (_Float16)u.y; r[2] = (_Float16)u.z; r[3] = (_Float16)u.w;
    r[4] = (_Float16)v.x; r[5] = (_Float16)v.y; r[6] = (_Float16)v.z; r[7] = (_Float16)v.w;
    return r;
}

// C[m][n] = sum_k A[m][k] * W[n][k] + bias[n];  M = gridDim.x*64, N = K = 256.
template<bool AF16>
__global__ __launch_bounds__(256, 2) void gemm_nt_256(
    const void* __restrict__ Av, const float* __restrict__ W,
    const float* __restrict__ bias, float* __restrict__ C) {
    const int tid = threadIdx.x;
    const int l  = tid & 63;
    const int w  = tid >> 6;
    const int lr = l & 15;
    const int lg = l >> 4;
    const long m0 = (long)blockIdx.x * 64;
    const int  n0 = w * 64;

    f32x4 acc[4][4] = {};

    #pragma unroll
    for (int k = 0; k < 8; ++k) {
        const int kc = k * 32 + lg * 8;
        f16x8 a[4], bf[4];
        #pragma unroll
        for (int mt = 0; mt < 4; ++mt) {
            const long row = m0 + mt * 16 + lr;
            if constexpr (AF16)
                a[mt] = *(const f16x8*)((const _Float16*)Av + row * 256 + kc);
            else
                a[mt] = cvt8((const float*)Av + row * 256 + kc);
        }
        #pragma unroll
        for (int nt = 0; nt < 4; ++nt)
            bf[nt] = cvt8(W + (long)(n0 + nt * 16 + lr) * 256 + kc);
        #pragma unroll
        for (int mt = 0; mt < 4; ++mt)
            #pragma unroll
            for (int nt = 0; nt < 4; ++nt)
                acc[mt][nt] = MFMA16(a[mt], bf[nt], acc[mt][nt], 0, 0, 0);
    }

    #pragma unroll
    for (int mt = 0; mt < 4; ++mt)
        #pragma unroll
        for (int nt = 0; nt < 4; ++nt) {
            const int col = n0 + nt * 16 + lr;
            const float bv = bias[col];
            #pragma unroll
            for (int d = 0; d < 4; ++d) {
                const long row = m0 + mt * 16 + lg * 4 + d;
                C[row * 256 + col] = acc[mt][nt][d] + bv;
            }
        }
}

// Recurrence: 32 blocks (1 batch each) x 512 threads (8 waves, 2/SIMD).
// Wave w owns 32 output cols. Whh B-fragments in registers. h broadcast via
// double-buffered LDS row; LDS-only barrier (no vmcnt drain).
// xh prefetched 4 steps deep (group-of-4 unroll) to cover ~900cy HBM latency.
__global__ __launch_bounds__(512, 2) void rnn_scan(
    const float* __restrict__ xh, const float* __restrict__ h0,
    const float* __restrict__ Whh, _Float16* __restrict__ hs,
    float* __restrict__ hfin) {
    const int b   = blockIdx.x;
    const int tid = threadIdx.x;
    const int l   = tid & 63;
    const int w   = tid >> 6;   // 0..7
    const int lr  = l & 15;
    const int lg  = l >> 4;
    const int n0  = w * 32;

    __shared__ _Float16 hbuf[2][256];

    // wb[nt][k] = Whh[n0+nt*16+lr][k*32+lg*8 .. +8]  (64 VGPR)
    f16x8 wb[2][8];
    #pragma unroll
    for (int nt = 0; nt < 2; ++nt)
        #pragma unroll
        for (int k = 0; k < 8; ++k)
            wb[nt][k] = cvt8(Whh + (long)(n0 + nt * 16 + lr) * 256 + k * 32 + lg * 8);

    if (tid < 256) hbuf[0][tid] = (_Float16)h0[b * 256 + tid];
    __syncthreads();

    const float* xp = xh + (long)b * 2048 * 256;

    // 4-step-deep xh prefetch (all indices compile-time after unroll)
    float xcur[4][2], xnext[4][2];
    #pragma unroll
    for (int j = 0; j < 4; ++j)
        #pragma unroll
        for (int nt = 0; nt < 2; ++nt)
            xcur[j][nt] = xp[(long)j * 256 + n0 + nt * 16 + lr];

    for (int tb = 0; tb < 2048; tb += 4) {
        // issue next group's loads now; consumed after 4 steps (~2500cy cover)
        #pragma unroll
        for (int j = 0; j < 4; ++j) {
            int tn = tb + 4 + j; if (tn > 2047) tn = 2047;
            #pragma unroll
            for (int nt = 0; nt < 2; ++nt)
                xnext[j][nt] = xp[(long)tn * 256 + n0 + nt * 16 + lr];
        }

        #pragma unroll
        for (int j = 0; j < 4; ++j) {
            const int t = tb + j;                       // t&1 == j&1 (tb%4==0)
            const f16x8* hc = (const f16x8*)hbuf[j & 1];
            f16x8 af[8];
            #pragma unroll
            for (int k = 0; k < 8; ++k) af[k] = hc[k * 4 + lg];

            const f32x4 zero = {0.f, 0.f, 0.f, 0.f};
            f32x4 accA[2], accB[2];                     // split chains: k0-3 / k4-7
            #pragma unroll
            for (int nt = 0; nt < 2; ++nt) {
                accA[nt] = MFMA16(af[0], wb[nt][0], zero, 0, 0, 0);
                accB[nt] = MFMA16(af[4], wb[nt][4], zero, 0, 0, 0);
            }
            #pragma unroll
            for (int k = 1; k < 4; ++k)
                #pragma unroll
                for (int nt = 0; nt < 2; ++nt) {
                    accA[nt] = MFMA16(af[k],     wb[nt][k],     accA[nt], 0, 0, 0);
                    accB[nt] = MFMA16(af[k + 4], wb[nt][k + 4], accB[nt], 0, 0, 0);
                }

            // tanh(s + xh) = 1 - 2/(exp(2s)+1)
            float tv[2];
            #pragma unroll
            for (int nt = 0; nt < 2; ++nt) {
                const float s = accA[nt][0] + accB[nt][0] + xcur[j][nt];
                const float e = __expf(2.0f * s);
                tv[nt] = 1.0f - 2.0f * __builtin_amdgcn_rcpf(e + 1.0f);
            }

            if (l < 32) {                               // one 64B contiguous segment
                const float v = (l & 16) ? tv[1] : tv[0];
                const _Float16 hv = (_Float16)v;
                hbuf[(j & 1) ^ 1][n0 + l] = hv;
                hs[((long)b * 2048 + t) * 256 + n0 + l] = hv;   // fire-and-forget
                if (t == 2047) hfin[b * 256 + n0 + l] = v;
            }

            asm volatile("s_waitcnt lgkmcnt(0)" ::: "memory");
            __builtin_amdgcn_s_barrier();
            asm volatile("" ::: "memory");
        }

        #pragma unroll
        for (int j = 0; j < 4; ++j) {
            xcur[j][0] = xnext[j][0];
            xcur[j][1] = xnext[j][1];
        }
    }
}

extern "C" void kernel_launch(void* const* d_in, const int* in_sizes, int n_in,
                              void* d_out, int out_size, void* d_ws, size_t ws_size,
                              hipStream_t stream) {
    const float* x   = (const float*)d_in[0];
    const float* h0  = (const float*)d_in[1];
    const float* Wxh = (const float*)d_in[2];
    const float* bxh = (const float*)d_in[3];
    const float* Whh = (const float*)d_in[4];
    const float* Why = (const float*)d_in[5];
    const float* by  = (const float*)d_in[6];

    float* y    = (float*)d_out;
    float* hfin = y + (long)65536 * 256;
    float* xh   = y;                       // xh scratch aliases y (dead before phase3 writes)
    _Float16* hs = (_Float16*)d_ws;

    gemm_nt_256<false><<<1024, 256, 0, stream>>>(x, Wxh, bxh, xh);
    rnn_scan<<<32, 512, 0, stream>>>(xh, h0, Whh, hs, hfin);
    gemm_nt_256<true><<<1024, 256, 0, stream>>>(hs, Why, by, y);
}